// Round 7
// baseline (296.953 us; speedup 1.0000x reference)
//
#include <hip/hip_runtime.h>
#include <stdint.h>

#define E_N 8192
#define SPLIT 8
#define CH 16                 // (E_N/SPLIT)/64 kv-chunks per split
#define QBLK 128

typedef unsigned short u16;
typedef unsigned int u32;
typedef unsigned long long u64;
typedef __attribute__((ext_vector_type(4))) float f32x4;
typedef __attribute__((ext_vector_type(8))) short bf16x8;
typedef __attribute__((ext_vector_type(4))) unsigned int u32x4;
typedef __attribute__((ext_vector_type(2))) unsigned int u32x2;

union V16 { u32x4 q; bf16x8 h; u16 u[8]; };

static __device__ __forceinline__ u16 f2bf(float f) {
  union { float f; unsigned u; } c; c.f = f;
  unsigned r = c.u + 0x7FFFu + ((c.u >> 16) & 1u);
  return (u16)(r >> 16);
}

// direct global->LDS async copy, 16B per lane; LDS dest is wave-uniform base + lane*16
#define GLDS16(gp, lp) __builtin_amdgcn_global_load_lds( \
    (const __attribute__((address_space(1))) u32*)(gp), \
    (__attribute__((address_space(3))) u32*)(u32)(uintptr_t)(lp), 16, 0, 0)

// q pre-scale folds softmax 1/sqrt(128) and log2(e) so inner loop is exp2.
constexpr float QS = 1.4426950408889634f / 11.313708498984761f;

// ---------- kernel 0: W[256][128] f32 -> Wt bf16 [2][128][256]
__global__ void k_wt(const float* __restrict__ Wq, const float* __restrict__ Wk,
                     u16* __restrict__ wt) {
  int idx = blockIdx.x * 256 + threadIdx.x;          // 0..65535
  int mat = idx >> 15, rem = idx & 32767;
  float v = mat ? Wk[rem] : Wq[rem];
  int d = rem >> 7, c = rem & 127;
  wt[(mat * 128 + c) * 256 + d] = f2bf(v);
}

// ---------- kernel 1: projections q (scaled) and k, bf16 [8192][128]
__launch_bounds__(256)
__global__ void k_proj(const float* __restrict__ X, const u16* __restrict__ wt,
                       u16* __restrict__ qg, u16* __restrict__ kg) {
  __shared__ __align__(16) char Xs[64 * 512];        // bf16 [64][256], xor-swizzled
  const int tid = threadIdx.x;
  const int wid = tid >> 6, lane = tid & 63, g = lane >> 4, l15 = lane & 15;
  const int r0 = blockIdx.x * 64;
#pragma unroll
  for (int i = 0; i < 16; ++i) {
    int s = tid + 256 * i;                           // 0..4095 float4 tasks
    int row = s >> 6, c4 = (s & 63) << 2;
    f32x4 v = *(const f32x4*)(X + (size_t)(r0 + row) * 256 + c4);
    u32x2 pk;
    pk[0] = f2bf(v[0]) | ((unsigned)f2bf(v[1]) << 16);
    pk[1] = f2bf(v[2]) | ((unsigned)f2bf(v[3]) << 16);
    *(u32x2*)(Xs + (((row << 9) + (c4 << 1)) ^ ((row & 7) << 4))) = pk;
  }
  __syncthreads();
  bf16x8 xa[8];
  const int arow = wid * 16 + l15;
#pragma unroll
  for (int ks = 0; ks < 8; ++ks) {
    V16 t; t.q = *(const u32x4*)(Xs + (((arow << 9) + (ks << 6) + (g << 4)) ^ ((l15 & 7) << 4)));
    xa[ks] = t.h;
  }
  const f32x4 zero4 = {0.f, 0.f, 0.f, 0.f};
  f32x4 acc[16];
#pragma unroll
  for (int i = 0; i < 16; ++i) acc[i] = zero4;
#pragma unroll
  for (int ct = 0; ct < 16; ++ct) {
    int mat = ct >> 3, c = ((ct & 7) << 4) + l15;
#pragma unroll
    for (int ks = 0; ks < 8; ++ks) {
      V16 b; b.q = *(const u32x4*)(wt + ((mat * 128 + c) * 256 + (ks << 5) + (g << 3)));
      acc[ct] = __builtin_amdgcn_mfma_f32_16x16x32_bf16(xa[ks], b.h, acc[ct], 0, 0, 0);
    }
  }
#pragma unroll
  for (int ct = 0; ct < 16; ++ct) {
    int mat = ct >> 3, c = ((ct & 7) << 4) + l15;
#pragma unroll
    for (int r = 0; r < 4; ++r) {
      int row = r0 + wid * 16 + 4 * g + r;
      float v = acc[ct][r];
      if (mat == 0) qg[row * 128 + c] = f2bf(v * QS);
      else          kg[row * 128 + c] = f2bf(v);
    }
  }
}

// ---------- kernel 2: kt[128][8192] = k^T (bf16), LDS-tiled transpose
__global__ void k_kt(const u16* __restrict__ kg, u16* __restrict__ ktg) {
  __shared__ __align__(16) u16 Ts[64 * 66];          // pitch 66 (132 B) for bank spread
  const int tid = threadIdx.x;
  const int b = blockIdx.x;
  const int r0 = (b >> 1) * 64, c0 = (b & 1) * 64;
#pragma unroll
  for (int i = 0; i < 2; ++i) {
    int s = tid + 256 * i;                           // 0..511
    int row = s >> 3, seg = s & 7;
    u32x4 v = *(const u32x4*)(kg + (size_t)(r0 + row) * 128 + c0 + seg * 8);
    unsigned* dst = (unsigned*)((char*)Ts + row * 132 + seg * 16);
    dst[0] = v[0]; dst[1] = v[1]; dst[2] = v[2]; dst[3] = v[3];
  }
  __syncthreads();
#pragma unroll
  for (int i = 0; i < 2; ++i) {
    int s = tid + 256 * i;
    int oc = s >> 3, seg2 = s & 7;
    u16 t[8];
#pragma unroll
    for (int j = 0; j < 8; ++j) t[j] = Ts[(seg2 * 8 + j) * 66 + oc];
    u32x4 o;
    o[0] = t[0] | ((unsigned)t[1] << 16);
    o[1] = t[2] | ((unsigned)t[3] << 16);
    o[2] = t[4] | ((unsigned)t[5] << 16);
    o[3] = t[6] | ((unsigned)t[7] << 16);
    *(u32x4*)(ktg + (size_t)(c0 + oc) * E_N + r0 + seg2 * 8) = o;
  }
}

// ---------- kernel 2b: pack mask int32 [8192][8192] -> bits, 16B/lane loads.
// Lane l reads cols 4l..4l+3 of a 256-col group it; ballot(c) gives u64 whose
// bit l is col it*256+4l+c. Row stride = 256 u32 (8192 bits).
// u32 addr = row*256 + it*8 + c*2 + half.
__launch_bounds__(256)
__global__ void k_pack(const int* __restrict__ M, u32* __restrict__ bits) {
  const int wid = threadIdx.x >> 6, lane = threadIdx.x & 63;
  const int row0 = blockIdx.x * 8 + wid * 2;
  const u32* p0 = (const u32*)M + (size_t)row0 * E_N + lane * 4;
  const u32* p1 = p0 + E_N;
  u32* q0 = bits + (size_t)row0 * 256;
  u32* q1 = q0 + 256;
#pragma unroll 2
  for (int it = 0; it < 32; ++it) {
    u32x4 a = *(const u32x4*)(p0 + it * 256);
    u32x4 b = *(const u32x4*)(p1 + it * 256);
    u64 a0 = __ballot(a[0] != 0), a1 = __ballot(a[1] != 0);
    u64 a2 = __ballot(a[2] != 0), a3 = __ballot(a[3] != 0);
    u64 b0 = __ballot(b[0] != 0), b1 = __ballot(b[1] != 0);
    u64 b2 = __ballot(b[2] != 0), b3 = __ballot(b[3] != 0);
    if (lane == 0) {
      u32x4 o;
      o[0] = (u32)a0; o[1] = (u32)(a0 >> 32); o[2] = (u32)a1; o[3] = (u32)(a1 >> 32);
      *(u32x4*)(q0 + it * 8) = o;
      o[0] = (u32)a2; o[1] = (u32)(a2 >> 32); o[2] = (u32)a3; o[3] = (u32)(a3 >> 32);
      *(u32x4*)(q0 + it * 8 + 4) = o;
      o[0] = (u32)b0; o[1] = (u32)(b0 >> 32); o[2] = (u32)b1; o[3] = (u32)(b1 >> 32);
      *(u32x4*)(q1 + it * 8) = o;
      o[0] = (u32)b2; o[1] = (u32)(b2 >> 32); o[2] = (u32)b3; o[3] = (u32)(b3 >> 32);
      *(u32x4*)(q1 + it * 8 + 4) = o;
    }
  }
}

// ---------- kernel 3 staging helper (scalar + LDS-pointer args only: no
// register arrays cross this boundary, so nothing can be forced to scratch)
__device__ __forceinline__ void stage_tiles(const u16* kg, const u16* ktg,
                                            char* Kbuf, char* Tbuf,
                                            int kv0, int wid, int lane) {
  const int krow_st = lane >> 4, kseg_st = lane & 15;  // K: 4 rows/chunk, 16 segs
  const int trow_st = lane >> 3, tseg_st = lane & 7;   // Kt: 8 rows/chunk, 8 segs
#pragma unroll
  for (int i = 0; i < 4; ++i) {
    int ch = i * 4 + wid;                              // wave-uniform chunk 0..15
    int row = ch * 4 + krow_st;
    int seg = kseg_st ^ (row & 7);
    GLDS16(kg + (size_t)(kv0 + row) * 128 + seg * 8, Kbuf + ch * 1024);
    int drow = ch * 8 + trow_st;
    int dseg = tseg_st ^ (drow & 7);
    GLDS16(ktg + (size_t)drow * E_N + kv0 + dseg * 8, Tbuf + ch * 1024);
  }
}

// One flash step, fully macro-expanded: buffer names and SUB are literals, all
// register-array indices are compile-time -> everything stays in registers.
#define FSTEP(SUB, KR, TR, KS, TS, DOPF)                                        \
  {                                                                             \
    if (DOPF)                                                                   \
      stage_tiles(kg, ktg, (KS), (TS), kvbase + (st0 + (SUB) + 1) * 64, wid, lane); \
    _Pragma("unroll")                                                           \
    for (int rt = 0; rt < 2; ++rt) {                                            \
      f32x4 S[4];                                                               \
      _Pragma("unroll")                                                         \
      for (int t = 0; t < 4; ++t) S[t] = zero4;                                 \
      _Pragma("unroll")                                                         \
      for (int t = 0; t < 4; ++t) {                                             \
        int krow = t * 16 + l15;                                                \
        _Pragma("unroll")                                                       \
        for (int ks = 0; ks < 4; ++ks) {                                        \
          V16 kf; kf.q = *(const u32x4*)((KR) + (((krow << 8) + (ks << 6) + (g << 4)) ^ ((l15 & 7) << 4))); \
          S[t] = __builtin_amdgcn_mfma_f32_16x16x32_bf16(qf[rt * 4 + ks], kf.h, S[t], 0, 0, 0); \
        }                                                                       \
      }                                                                         \
      _Pragma("unroll")                                                         \
      for (int t = 0; t < 4; ++t) {                                             \
        _Pragma("unroll")                                                       \
        for (int r = 0; r < 4; ++r) {                                           \
          u32 w = ((SUB) & 2) ? wc[rt * 4 + r][1] : wc[rt * 4 + r][0];          \
          float pv = ((w >> (((SUB) & 1) * 16 + t * 4 + q2)) & 1u)              \
                         ? __builtin_amdgcn_exp2f(S[t][r]) : 0.f;               \
          lacc[rt * 4 + r] += pv;                                               \
          int prow = 4 * g + r;                                                 \
          *(u16*)(Pw + ((prow * 128 + (t * 16 + l15) * 2) ^ ((prow & 7) << 4))) = f2bf(pv); \
        }                                                                       \
      }                                                                         \
      bf16x8 pa0, pa1;                                                          \
      { V16 t2; t2.q = *(const u32x4*)(Pw + ((l15 * 128 + g * 16) ^ ((l15 & 7) << 4))); pa0 = t2.h; } \
      { V16 t2; t2.q = *(const u32x4*)(Pw + ((l15 * 128 + 64 + g * 16) ^ ((l15 & 7) << 4))); pa1 = t2.h; } \
      _Pragma("unroll")                                                         \
      for (int dt = 0; dt < 8; ++dt) {                                          \
        int krow = dt * 16 + l15;                                               \
        V16 kf0; kf0.q = *(const u32x4*)((TR) + (((krow << 7) + (g << 4)) ^ ((l15 & 7) << 4))); \
        Oacc[rt * 8 + dt] = __builtin_amdgcn_mfma_f32_16x16x32_bf16(pa0, kf0.h, Oacc[rt * 8 + dt], 0, 0, 0); \
        V16 kf1; kf1.q = *(const u32x4*)((TR) + (((krow << 7) + 64 + (g << 4)) ^ ((l15 & 7) << 4))); \
        Oacc[rt * 8 + dt] = __builtin_amdgcn_mfma_f32_16x16x32_bf16(pa1, kf1.h, Oacc[rt * 8 + dt], 0, 0, 0); \
      }                                                                         \
    }                                                                           \
    __syncthreads();                                                            \
  }

// ---------- kernel 3: fused masked-softmax attention, double-buffered tiles.
// grid 512: split = bid&7 (XCD-aligned under round-robin dispatch), qb = bid>>3.
// All 64 same-split blocks stream the same chunk together -> per-XCD L2 working
// set ~64 KB, first-touch misses only.
// amdgpu_waves_per_eu(2,2): pin allocator target to 2 waves/EU (256 unified
// VGPRs) -- launch_bounds(256,2) alone let it target 4 waves/EU (128 regs)
// and spill ~260 MB/dir of scratch (rounds 5-6 counter evidence).
__launch_bounds__(256)
__attribute__((amdgpu_waves_per_eu(2, 2)))
__global__ void k_flash(const u16* __restrict__ qg, const u16* __restrict__ kg,
                        const u16* __restrict__ ktg, const u32* __restrict__ bits,
                        float* __restrict__ Op, float* __restrict__ lp) {
  __shared__ __align__(16) char K0[64 * 256], K1[64 * 256];   // 2x16 KB
  __shared__ __align__(16) char T0[128 * 128], T1[128 * 128]; // 2x16 KB
  __shared__ __align__(16) char Psh[4 * 2048];                // per-wave P tile
  const int tid = threadIdx.x;
  const int wid = tid >> 6, lane = tid & 63, g = lane >> 4, l15 = lane & 15;
  const int q2 = l15 >> 2;
  const int bid = blockIdx.x;
  const int split = bid & 7, qb = bid >> 3;
  const int qb0 = qb * QBLK;
  const int kvbase = split * (E_N / SPLIT);
  char* Pw = Psh + wid * 2048;
  const u32* mbase = bits + (size_t)(qb0 + wid * 32 + 4 * g) * 256 + split * 32 + (l15 & 3) * 2;

  bf16x8 qf[8];
#pragma unroll
  for (int rt = 0; rt < 2; ++rt) {
    const u16* qrow = qg + (size_t)(qb0 + wid * 32 + rt * 16 + l15) * 128;
#pragma unroll
    for (int ks = 0; ks < 4; ++ks) {
      V16 t; t.q = *(const u32x4*)(qrow + (ks << 5) + (g << 3));
      qf[rt * 4 + ks] = t.h;
    }
  }
  const f32x4 zero4 = {0.f, 0.f, 0.f, 0.f};
  f32x4 Oacc[16];
#pragma unroll
  for (int i = 0; i < 16; ++i) Oacc[i] = zero4;
  float lacc[8] = {0.f, 0.f, 0.f, 0.f, 0.f, 0.f, 0.f, 0.f};
  u32x2 wc[8];

  stage_tiles(kg, ktg, K0, T0, kvbase, wid, lane);
  __syncthreads();

  for (int grp = 0; grp < 4; ++grp) {
    const int st0 = grp * 4;
    // mask words for this group's 4 steps (u32x2 per q-row covers 256 cols)
#pragma unroll
    for (int i = 0; i < 8; ++i)
      wc[i] = *(const u32x2*)(mbase + ((i >> 2) * 16 + (i & 3)) * 256 + grp * 8);
    FSTEP(0, K0, T0, K1, T1, true)
    FSTEP(1, K1, T1, K0, T0, true)
    FSTEP(2, K0, T0, K1, T1, true)
    FSTEP(3, K1, T1, K0, T0, (grp < 3))
  }

  // reduce row sums across the 16 lanes of each group
#pragma unroll
  for (int i = 0; i < 8; ++i) {
    float v = lacc[i];
    v += __shfl_xor(v, 1);
    v += __shfl_xor(v, 2);
    v += __shfl_xor(v, 4);
    v += __shfl_xor(v, 8);
    lacc[i] = v;
  }
  if (l15 == 0) {
#pragma unroll
    for (int i = 0; i < 8; ++i)
      lp[split * E_N + qb0 + wid * 32 + (i >> 2) * 16 + 4 * g + (i & 3)] = lacc[i];
  }
#pragma unroll
  for (int rt = 0; rt < 2; ++rt) {
    float* op = Op + ((size_t)split * E_N + qb0 + wid * 32 + rt * 16) * 128;
#pragma unroll
    for (int dt = 0; dt < 8; ++dt)
#pragma unroll
      for (int r = 0; r < 4; ++r)
        op[(4 * g + r) * 128 + dt * 16 + l15] = Oacc[rt * 8 + dt][r];
  }
}

// ---------- kernel 4: combine KV-split partials, normalize (float4)
__global__ void k_comb(const float* __restrict__ Op, const float* __restrict__ lp,
                       float* __restrict__ out) {
  int idx4 = blockIdx.x * 256 + threadIdx.x;       // < 8192*128/4
  int base = idx4 << 2;
  int e = base >> 7;
  f32x4 o = {0.f, 0.f, 0.f, 0.f};
  float l = 0.f;
#pragma unroll
  for (int s = 0; s < SPLIT; ++s) {
    o += *(const f32x4*)(Op + (size_t)s * (E_N * 128) + base);
    l += lp[s * E_N + e];
  }
  float rl = 1.0f / l;
  o[0] *= rl; o[1] *= rl; o[2] *= rl; o[3] *= rl;
  *(f32x4*)(out + base) = o;
}

extern "C" void kernel_launch(void* const* d_in, const int* in_sizes, int n_in,
                              void* d_out, int out_size, void* d_ws, size_t ws_size,
                              hipStream_t stream) {
  const float* X  = (const float*)d_in[0];
  const float* Wq = (const float*)d_in[1];
  const float* Wk = (const float*)d_in[2];
  const int*   M  = (const int*)d_in[3];
  char* ws = (char*)d_ws;
  u16*   qg   = (u16*)(ws);                                       // 2 MB
  u16*   kg   = (u16*)(ws + (size_t)(2u << 20));                  // 2 MB
  u16*   ktg  = (u16*)(ws + (size_t)(4u << 20));                  // 2 MB
  u16*   wt   = (u16*)(ws + (size_t)(6u << 20));                  // 128 KB
  float* lp   = (float*)(ws + (size_t)(6u << 20) + (128u << 10)); // 256 KB
  u32*   bits = (u32*)(ws + (size_t)(6u << 20) + (512u << 10));   // 8 MB @ 6.5 MB
  float* Op   = (float*)(ws + (size_t)(6u << 20) + (512u << 10) + (8u << 20)); // 32 MB @ 14.5 MB
  float* out = (float*)d_out;

  k_wt  <<<256, 256, 0, stream>>>(Wq, Wk, wt);
  k_proj<<<128, 256, 0, stream>>>(X, wt, qg, kg);
  k_kt  <<<256, 256, 0, stream>>>(kg, ktg);
  k_pack<<<E_N / 8, 256, 0, stream>>>(M, bits);
  k_flash<<<SPLIT * (E_N / QBLK), 256, 0, stream>>>(qg, kg, ktg, bits, Op, lp);
  k_comb<<<(E_N * 128 / 4) / 256, 256, 0, stream>>>(Op, lp, out);
}

// Round 8
// 162.191 us; speedup vs baseline: 1.8309x; 1.8309x over previous
//
#include <hip/hip_runtime.h>
#include <stdint.h>

#define E_N 8192
#define SPLIT 8
#define CH 16                 // (E_N/SPLIT)/64 kv-chunks per split
#define QBLK 64

typedef unsigned short u16;
typedef unsigned int u32;
typedef unsigned long long u64;
typedef __attribute__((ext_vector_type(4))) float f32x4;
typedef __attribute__((ext_vector_type(8))) short bf16x8;
typedef __attribute__((ext_vector_type(4))) unsigned int u32x4;
typedef __attribute__((ext_vector_type(2))) unsigned int u32x2;

union V16 { u32x4 q; bf16x8 h; u16 u[8]; };

static __device__ __forceinline__ u16 f2bf(float f) {
  union { float f; unsigned u; } c; c.f = f;
  unsigned r = c.u + 0x7FFFu + ((c.u >> 16) & 1u);
  return (u16)(r >> 16);
}

// q pre-scale folds softmax 1/sqrt(128) and log2(e) so inner loop is exp2.
constexpr float QS = 1.4426950408889634f / 11.313708498984761f;

// ---------- kernel 0: W[256][128] f32 -> Wt bf16 [2][128][256]
__global__ void k_wt(const float* __restrict__ Wq, const float* __restrict__ Wk,
                     u16* __restrict__ wt) {
  int idx = blockIdx.x * 256 + threadIdx.x;          // 0..65535
  int mat = idx >> 15, rem = idx & 32767;
  float v = mat ? Wk[rem] : Wq[rem];
  int d = rem >> 7, c = rem & 127;
  wt[(mat * 128 + c) * 256 + d] = f2bf(v);
}

// ---------- kernel 1: projections q (scaled) and k, bf16 [8192][128]
__launch_bounds__(256)
__global__ void k_proj(const float* __restrict__ X, const u16* __restrict__ wt,
                       u16* __restrict__ qg, u16* __restrict__ kg) {
  __shared__ __align__(16) char Xs[64 * 512];        // bf16 [64][256], xor-swizzled
  const int tid = threadIdx.x;
  const int wid = tid >> 6, lane = tid & 63, g = lane >> 4, l15 = lane & 15;
  const int r0 = blockIdx.x * 64;
#pragma unroll
  for (int i = 0; i < 16; ++i) {
    int s = tid + 256 * i;                           // 0..4095 float4 tasks
    int row = s >> 6, c4 = (s & 63) << 2;
    f32x4 v = *(const f32x4*)(X + (size_t)(r0 + row) * 256 + c4);
    u32x2 pk;
    pk[0] = f2bf(v[0]) | ((unsigned)f2bf(v[1]) << 16);
    pk[1] = f2bf(v[2]) | ((unsigned)f2bf(v[3]) << 16);
    *(u32x2*)(Xs + (((row << 9) + (c4 << 1)) ^ ((row & 7) << 4))) = pk;
  }
  __syncthreads();
  bf16x8 xa[8];
  const int arow = wid * 16 + l15;
#pragma unroll
  for (int ks = 0; ks < 8; ++ks) {
    V16 t; t.q = *(const u32x4*)(Xs + (((arow << 9) + (ks << 6) + (g << 4)) ^ ((l15 & 7) << 4)));
    xa[ks] = t.h;
  }
  const f32x4 zero4 = {0.f, 0.f, 0.f, 0.f};
  f32x4 acc[16];
#pragma unroll
  for (int i = 0; i < 16; ++i) acc[i] = zero4;
#pragma unroll
  for (int ct = 0; ct < 16; ++ct) {
    int mat = ct >> 3, c = ((ct & 7) << 4) + l15;
#pragma unroll
    for (int ks = 0; ks < 8; ++ks) {
      V16 b; b.q = *(const u32x4*)(wt + ((mat * 128 + c) * 256 + (ks << 5) + (g << 3)));
      acc[ct] = __builtin_amdgcn_mfma_f32_16x16x32_bf16(xa[ks], b.h, acc[ct], 0, 0, 0);
    }
  }
#pragma unroll
  for (int ct = 0; ct < 16; ++ct) {
    int mat = ct >> 3, c = ((ct & 7) << 4) + l15;
#pragma unroll
    for (int r = 0; r < 4; ++r) {
      int row = r0 + wid * 16 + 4 * g + r;
      float v = acc[ct][r];
      if (mat == 0) qg[row * 128 + c] = f2bf(v * QS);
      else          kg[row * 128 + c] = f2bf(v);
    }
  }
}

// ---------- kernel 2: kt[128][8192] = k^T (bf16), LDS-tiled transpose
__global__ void k_kt(const u16* __restrict__ kg, u16* __restrict__ ktg) {
  __shared__ __align__(16) u16 Ts[64 * 66];          // pitch 66 (132 B) for bank spread
  const int tid = threadIdx.x;
  const int b = blockIdx.x;
  const int r0 = (b >> 1) * 64, c0 = (b & 1) * 64;
#pragma unroll
  for (int i = 0; i < 2; ++i) {
    int s = tid + 256 * i;                           // 0..511
    int row = s >> 3, seg = s & 7;
    u32x4 v = *(const u32x4*)(kg + (size_t)(r0 + row) * 128 + c0 + seg * 8);
    unsigned* dst = (unsigned*)((char*)Ts + row * 132 + seg * 16);
    dst[0] = v[0]; dst[1] = v[1]; dst[2] = v[2]; dst[3] = v[3];
  }
  __syncthreads();
#pragma unroll
  for (int i = 0; i < 2; ++i) {
    int s = tid + 256 * i;
    int oc = s >> 3, seg2 = s & 7;
    u16 t[8];
#pragma unroll
    for (int j = 0; j < 8; ++j) t[j] = Ts[(seg2 * 8 + j) * 66 + oc];
    u32x4 o;
    o[0] = t[0] | ((unsigned)t[1] << 16);
    o[1] = t[2] | ((unsigned)t[3] << 16);
    o[2] = t[4] | ((unsigned)t[5] << 16);
    o[3] = t[6] | ((unsigned)t[7] << 16);
    *(u32x4*)(ktg + (size_t)(c0 + oc) * E_N + r0 + seg2 * 8) = o;
  }
}

// ---------- kernel 2b: pack mask int32 [8192][8192] -> bits, 16B/lane loads.
// Lane l reads cols 4l..4l+3 of a 256-col group it; ballot(c) gives u64 whose
// bit l is col it*256+4l+c. Row stride = 256 u32 (8192 bits).
__launch_bounds__(256)
__global__ void k_pack(const int* __restrict__ M, u32* __restrict__ bits) {
  const int wid = threadIdx.x >> 6, lane = threadIdx.x & 63;
  const int row0 = blockIdx.x * 8 + wid * 2;
  const u32* p0 = (const u32*)M + (size_t)row0 * E_N + lane * 4;
  const u32* p1 = p0 + E_N;
  u32* q0 = bits + (size_t)row0 * 256;
  u32* q1 = q0 + 256;
#pragma unroll 2
  for (int it = 0; it < 32; ++it) {
    u32x4 a = *(const u32x4*)(p0 + it * 256);
    u32x4 b = *(const u32x4*)(p1 + it * 256);
    u64 a0 = __ballot(a[0] != 0), a1 = __ballot(a[1] != 0);
    u64 a2 = __ballot(a[2] != 0), a3 = __ballot(a[3] != 0);
    u64 b0 = __ballot(b[0] != 0), b1 = __ballot(b[1] != 0);
    u64 b2 = __ballot(b[2] != 0), b3 = __ballot(b[3] != 0);
    if (lane == 0) {
      u32x4 o;
      o[0] = (u32)a0; o[1] = (u32)(a0 >> 32); o[2] = (u32)a1; o[3] = (u32)(a1 >> 32);
      *(u32x4*)(q0 + it * 8) = o;
      o[0] = (u32)a2; o[1] = (u32)(a2 >> 32); o[2] = (u32)a3; o[3] = (u32)(a3 >> 32);
      *(u32x4*)(q0 + it * 8 + 4) = o;
      o[0] = (u32)b0; o[1] = (u32)(b0 >> 32); o[2] = (u32)b1; o[3] = (u32)(b1 >> 32);
      *(u32x4*)(q1 + it * 8) = o;
      o[0] = (u32)b2; o[1] = (u32)(b2 >> 32); o[2] = (u32)b3; o[3] = (u32)(b3 >> 32);
      *(u32x4*)(q1 + it * 8 + 4) = o;
    }
  }
}

// Reg-staged tile load: 8 x global dwordx4 into named regs (L2-allocating,
// unlike global_load_lds whose fetches got 0% L2 hit across rounds 2-7).
#define LOADREGS(KV1)                                                           \
  {                                                                             \
    const u16* kp = kgp + (size_t)(KV1) * 128;                                  \
    kr0 = *(const u32x4*)(kp);                                                  \
    kr1 = *(const u32x4*)(kp + 16 * 128);                                       \
    kr2 = *(const u32x4*)(kp + 32 * 128);                                       \
    kr3 = *(const u32x4*)(kp + 48 * 128);                                       \
    const u16* tp = ktp + (KV1);                                                \
    tr0 = *(const u32x4*)(tp);                                                  \
    tr1 = *(const u32x4*)(tp + 32 * E_N);                                       \
    tr2 = *(const u32x4*)(tp + 64 * E_N);                                       \
    tr3 = *(const u32x4*)(tp + 96 * E_N);                                       \
  }

#define WRITELDS(KW, TW)                                                        \
  {                                                                             \
    *(u32x4*)((KW) + kofs)          = kr0;                                      \
    *(u32x4*)((KW) + kofs + 4096)   = kr1;                                      \
    *(u32x4*)((KW) + kofs + 8192)   = kr2;                                      \
    *(u32x4*)((KW) + kofs + 12288)  = kr3;                                      \
    *(u32x4*)((TW) + tofs)          = tr0;                                      \
    *(u32x4*)((TW) + tofs + 4096)   = tr1;                                      \
    *(u32x4*)((TW) + tofs + 8192)   = tr2;                                      \
    *(u32x4*)((TW) + tofs + 12288)  = tr3;                                      \
  }

// One flash step: issue next-tile loads, compute on current buffers, barrier,
// ds_write next tile into the other buffers, barrier. All indices literal.
#define FSTEP(SUB, KR, TR, KW, TW, DOPF)                                        \
  {                                                                             \
    if (DOPF) LOADREGS(kvbase + (st0 + (SUB) + 1) * 64)                         \
    f32x4 S[4];                                                                 \
    _Pragma("unroll")                                                           \
    for (int t = 0; t < 4; ++t) S[t] = zero4;                                   \
    _Pragma("unroll")                                                           \
    for (int t = 0; t < 4; ++t) {                                               \
      int krow = t * 16 + l15;                                                  \
      _Pragma("unroll")                                                         \
      for (int ks = 0; ks < 4; ++ks) {                                          \
        V16 kf; kf.q = *(const u32x4*)((KR) + (((krow << 8) + (ks << 6) + (g << 4)) ^ ((l15 & 7) << 4))); \
        S[t] = __builtin_amdgcn_mfma_f32_16x16x32_bf16(qf[ks], kf.h, S[t], 0, 0, 0); \
      }                                                                         \
    }                                                                           \
    _Pragma("unroll")                                                           \
    for (int t = 0; t < 4; ++t) {                                               \
      _Pragma("unroll")                                                         \
      for (int r = 0; r < 4; ++r) {                                             \
        u32 w = ((SUB) & 2) ? wc[r][1] : wc[r][0];                              \
        float pv = ((w >> (((SUB) & 1) * 16 + t * 4 + q2)) & 1u)                \
                       ? __builtin_amdgcn_exp2f(S[t][r]) : 0.f;                 \
        lacc[r] += pv;                                                          \
        int prow = 4 * g + r;                                                   \
        *(u16*)(Pw + ((prow * 128 + (t * 16 + l15) * 2) ^ ((prow & 7) << 4))) = f2bf(pv); \
      }                                                                         \
    }                                                                           \
    bf16x8 pa0, pa1;                                                            \
    { V16 t2; t2.q = *(const u32x4*)(Pw + ((l15 * 128 + g * 16) ^ ((l15 & 7) << 4))); pa0 = t2.h; } \
    { V16 t2; t2.q = *(const u32x4*)(Pw + ((l15 * 128 + 64 + g * 16) ^ ((l15 & 7) << 4))); pa1 = t2.h; } \
    _Pragma("unroll")                                                           \
    for (int dt = 0; dt < 8; ++dt) {                                            \
      int krow = dt * 16 + l15;                                                 \
      V16 kf0; kf0.q = *(const u32x4*)((TR) + (((krow << 7) + (g << 4)) ^ ((l15 & 7) << 4))); \
      Oacc[dt] = __builtin_amdgcn_mfma_f32_16x16x32_bf16(pa0, kf0.h, Oacc[dt], 0, 0, 0); \
      V16 kf1; kf1.q = *(const u32x4*)((TR) + (((krow << 7) + 64 + (g << 4)) ^ ((l15 & 7) << 4))); \
      Oacc[dt] = __builtin_amdgcn_mfma_f32_16x16x32_bf16(pa1, kf1.h, Oacc[dt], 0, 0, 0); \
    }                                                                           \
    __syncthreads();                                                            \
    if (DOPF) WRITELDS(KW, TW)                                                  \
    __syncthreads();                                                            \
  }

// ---------- kernel 3: fused masked-softmax attention, reg-staged dbuf tiles.
// grid 1024: split = bid&7 (XCD-aligned under round-robin dispatch), qb=bid>>3.
// Per-split K/Kt slice = 512 KB, L2-resident once regular loads allocate it.
__launch_bounds__(256, 2)
__global__ void k_flash(const u16* __restrict__ qg, const u16* __restrict__ kg,
                        const u16* __restrict__ ktg, const u32* __restrict__ bits,
                        float* __restrict__ Op, float* __restrict__ lp) {
  __shared__ __align__(16) char K0[64 * 256], K1[64 * 256];   // 2x16 KB
  __shared__ __align__(16) char T0[128 * 128], T1[128 * 128]; // 2x16 KB
  __shared__ __align__(16) char Psh[4 * 2048];                // per-wave P tile
  const int tid = threadIdx.x;
  const int wid = tid >> 6, lane = tid & 63, g = lane >> 4, l15 = lane & 15;
  const int q2 = l15 >> 2;
  const int bid = blockIdx.x;
  const int split = bid & 7, qb = bid >> 3;
  const int qb0 = qb * QBLK;
  const int kvbase = split * (E_N / SPLIT);
  char* Pw = Psh + wid * 2048;
  const u32* mbase = bits + (size_t)(qb0 + wid * 16 + 4 * g) * 256 + split * 32 + (l15 & 3) * 2;

  // staging lane geometry (swizzled LDS dest, linear global source)
  const int kr_r = tid >> 4, kr_s = tid & 15;   // K: rows kr_r+16i, 16B seg kr_s
  const int tr_d = tid >> 3, tr_s = tid & 7;    // Kt: d tr_d+32i, 16B seg tr_s
  const int kofs = ((kr_r << 8) + (kr_s << 4)) ^ ((kr_r & 7) << 4);
  const int tofs = ((tr_d << 7) + (tr_s << 4)) ^ ((tr_d & 7) << 4);
  const u16* kgp = kg + (size_t)kr_r * 128 + kr_s * 8;
  const u16* ktp = ktg + (size_t)tr_d * E_N + tr_s * 8;
  u32x4 kr0, kr1, kr2, kr3, tr0, tr1, tr2, tr3;

  bf16x8 qf[4];
  {
    const u16* qrow = qg + (size_t)(qb0 + wid * 16 + l15) * 128;
#pragma unroll
    for (int ks = 0; ks < 4; ++ks) {
      V16 t; t.q = *(const u32x4*)(qrow + (ks << 5) + (g << 3));
      qf[ks] = t.h;
    }
  }
  const f32x4 zero4 = {0.f, 0.f, 0.f, 0.f};
  f32x4 Oacc[8];
#pragma unroll
  for (int i = 0; i < 8; ++i) Oacc[i] = zero4;
  float lacc[4] = {0.f, 0.f, 0.f, 0.f};
  u32x2 wc[4];

  LOADREGS(kvbase)
  WRITELDS(K0, T0)
  __syncthreads();

  for (int grp = 0; grp < 4; ++grp) {
    const int st0 = grp * 4;
    // mask words for this group's 4 steps (u32x2 per q-row covers 256 cols)
#pragma unroll
    for (int r = 0; r < 4; ++r)
      wc[r] = *(const u32x2*)(mbase + r * 256 + grp * 8);
    FSTEP(0, K0, T0, K1, T1, true)
    FSTEP(1, K1, T1, K0, T0, true)
    FSTEP(2, K0, T0, K1, T1, true)
    FSTEP(3, K1, T1, K0, T0, (grp < 3))
  }

  // reduce row sums across the 16 lanes of each group
#pragma unroll
  for (int r = 0; r < 4; ++r) {
    float v = lacc[r];
    v += __shfl_xor(v, 1);
    v += __shfl_xor(v, 2);
    v += __shfl_xor(v, 4);
    v += __shfl_xor(v, 8);
    lacc[r] = v;
  }
  if (l15 == 0) {
#pragma unroll
    for (int r = 0; r < 4; ++r)
      lp[split * E_N + qb0 + wid * 16 + 4 * g + r] = lacc[r];
  }
  float* op = Op + ((size_t)split * E_N + qb0 + wid * 16) * 128;
#pragma unroll
  for (int dt = 0; dt < 8; ++dt)
#pragma unroll
    for (int r = 0; r < 4; ++r)
      op[(4 * g + r) * 128 + dt * 16 + l15] = Oacc[dt][r];
}

// ---------- kernel 4: combine KV-split partials, normalize (float4)
__global__ void k_comb(const float* __restrict__ Op, const float* __restrict__ lp,
                       float* __restrict__ out) {
  int idx4 = blockIdx.x * 256 + threadIdx.x;       // < 8192*128/4
  int base = idx4 << 2;
  int e = base >> 7;
  f32x4 o = {0.f, 0.f, 0.f, 0.f};
  float l = 0.f;
#pragma unroll
  for (int s = 0; s < SPLIT; ++s) {
    o += *(const f32x4*)(Op + (size_t)s * (E_N * 128) + base);
    l += lp[s * E_N + e];
  }
  float rl = 1.0f / l;
  o[0] *= rl; o[1] *= rl; o[2] *= rl; o[3] *= rl;
  *(f32x4*)(out + base) = o;
}

extern "C" void kernel_launch(void* const* d_in, const int* in_sizes, int n_in,
                              void* d_out, int out_size, void* d_ws, size_t ws_size,
                              hipStream_t stream) {
  const float* X  = (const float*)d_in[0];
  const float* Wq = (const float*)d_in[1];
  const float* Wk = (const float*)d_in[2];
  const int*   M  = (const int*)d_in[3];
  char* ws = (char*)d_ws;
  u16*   qg   = (u16*)(ws);                                       // 2 MB
  u16*   kg   = (u16*)(ws + (size_t)(2u << 20));                  // 2 MB
  u16*   ktg  = (u16*)(ws + (size_t)(4u << 20));                  // 2 MB
  u16*   wt   = (u16*)(ws + (size_t)(6u << 20));                  // 128 KB
  float* lp   = (float*)(ws + (size_t)(6u << 20) + (128u << 10)); // 256 KB
  u32*   bits = (u32*)(ws + (size_t)(6u << 20) + (512u << 10));   // 8 MB @ 6.5 MB
  float* Op   = (float*)(ws + (size_t)(6u << 20) + (512u << 10) + (8u << 20)); // 32 MB @ 14.5 MB
  float* out = (float*)d_out;

  k_wt  <<<256, 256, 0, stream>>>(Wq, Wk, wt);
  k_proj<<<128, 256, 0, stream>>>(X, wt, qg, kg);
  k_kt  <<<256, 256, 0, stream>>>(kg, ktg);
  k_pack<<<E_N / 8, 256, 0, stream>>>(M, bits);
  k_flash<<<SPLIT * (E_N / QBLK), 256, 0, stream>>>(qg, kg, ktg, bits, Op, lp);
  k_comb<<<(E_N * 128 / 4) / 256, 256, 0, stream>>>(Op, lp, out);
}

// Round 9
// 134.577 us; speedup vs baseline: 2.2066x; 1.2052x over previous
//
#include <hip/hip_runtime.h>
#include <stdint.h>

#define E_N 8192
#define SPLIT 8
#define CH 16                 // (E_N/SPLIT)/64 kv-chunks per split
#define QBLK 64

typedef unsigned short u16;
typedef unsigned int u32;
typedef unsigned long long u64;
typedef __attribute__((ext_vector_type(4))) float f32x4;
typedef __attribute__((ext_vector_type(8))) short bf16x8;
typedef __attribute__((ext_vector_type(4))) unsigned int u32x4;
typedef __attribute__((ext_vector_type(2))) unsigned int u32x2;

union V16 { u32x4 q; bf16x8 h; u16 u[8]; };

static __device__ __forceinline__ u16 f2bf(float f) {
  union { float f; unsigned u; } c; c.f = f;
  unsigned r = c.u + 0x7FFFu + ((c.u >> 16) & 1u);
  return (u16)(r >> 16);
}

// q pre-scale folds softmax 1/sqrt(128) and log2(e) so inner loop is exp2.
constexpr float QS = 1.4426950408889634f / 11.313708498984761f;

// ---------- kernel 0: W[256][128] f32 -> Wt bf16 [2][128][256]
__global__ void k_wt(const float* __restrict__ Wq, const float* __restrict__ Wk,
                     u16* __restrict__ wt) {
  int idx = blockIdx.x * 256 + threadIdx.x;          // 0..65535
  int mat = idx >> 15, rem = idx & 32767;
  float v = mat ? Wk[rem] : Wq[rem];
  int d = rem >> 7, c = rem & 127;
  wt[(mat * 128 + c) * 256 + d] = f2bf(v);
}

// ---------- kernel 1: projections q (scaled) and k, bf16 [8192][128]
__launch_bounds__(256)
__global__ void k_proj(const float* __restrict__ X, const u16* __restrict__ wt,
                       u16* __restrict__ qg, u16* __restrict__ kg) {
  __shared__ __align__(16) char Xs[64 * 512];        // bf16 [64][256], xor-swizzled
  const int tid = threadIdx.x;
  const int wid = tid >> 6, lane = tid & 63, g = lane >> 4, l15 = lane & 15;
  const int r0 = blockIdx.x * 64;
#pragma unroll
  for (int i = 0; i < 16; ++i) {
    int s = tid + 256 * i;                           // 0..4095 float4 tasks
    int row = s >> 6, c4 = (s & 63) << 2;
    f32x4 v = *(const f32x4*)(X + (size_t)(r0 + row) * 256 + c4);
    u32x2 pk;
    pk[0] = f2bf(v[0]) | ((unsigned)f2bf(v[1]) << 16);
    pk[1] = f2bf(v[2]) | ((unsigned)f2bf(v[3]) << 16);
    *(u32x2*)(Xs + (((row << 9) + (c4 << 1)) ^ ((row & 7) << 4))) = pk;
  }
  __syncthreads();
  bf16x8 xa[8];
  const int arow = wid * 16 + l15;
#pragma unroll
  for (int ks = 0; ks < 8; ++ks) {
    V16 t; t.q = *(const u32x4*)(Xs + (((arow << 9) + (ks << 6) + (g << 4)) ^ ((l15 & 7) << 4)));
    xa[ks] = t.h;
  }
  const f32x4 zero4 = {0.f, 0.f, 0.f, 0.f};
  f32x4 acc[16];
#pragma unroll
  for (int i = 0; i < 16; ++i) acc[i] = zero4;
#pragma unroll
  for (int ct = 0; ct < 16; ++ct) {
    int mat = ct >> 3, c = ((ct & 7) << 4) + l15;
#pragma unroll
    for (int ks = 0; ks < 8; ++ks) {
      V16 b; b.q = *(const u32x4*)(wt + ((mat * 128 + c) * 256 + (ks << 5) + (g << 3)));
      acc[ct] = __builtin_amdgcn_mfma_f32_16x16x32_bf16(xa[ks], b.h, acc[ct], 0, 0, 0);
    }
  }
#pragma unroll
  for (int ct = 0; ct < 16; ++ct) {
    int mat = ct >> 3, c = ((ct & 7) << 4) + l15;
#pragma unroll
    for (int r = 0; r < 4; ++r) {
      int row = r0 + wid * 16 + 4 * g + r;
      float v = acc[ct][r];
      if (mat == 0) qg[row * 128 + c] = f2bf(v * QS);
      else          kg[row * 128 + c] = f2bf(v);
    }
  }
}

// ---------- kernel 2: kt[128][8192] = k^T (bf16), LDS-tiled transpose
__global__ void k_kt(const u16* __restrict__ kg, u16* __restrict__ ktg) {
  __shared__ __align__(16) u16 Ts[64 * 66];          // pitch 66 (132 B) for bank spread
  const int tid = threadIdx.x;
  const int b = blockIdx.x;
  const int r0 = (b >> 1) * 64, c0 = (b & 1) * 64;
#pragma unroll
  for (int i = 0; i < 2; ++i) {
    int s = tid + 256 * i;                           // 0..511
    int row = s >> 3, seg = s & 7;
    u32x4 v = *(const u32x4*)(kg + (size_t)(r0 + row) * 128 + c0 + seg * 8);
    unsigned* dst = (unsigned*)((char*)Ts + row * 132 + seg * 16);
    dst[0] = v[0]; dst[1] = v[1]; dst[2] = v[2]; dst[3] = v[3];
  }
  __syncthreads();
#pragma unroll
  for (int i = 0; i < 2; ++i) {
    int s = tid + 256 * i;
    int oc = s >> 3, seg2 = s & 7;
    u16 t[8];
#pragma unroll
    for (int j = 0; j < 8; ++j) t[j] = Ts[(seg2 * 8 + j) * 66 + oc];
    u32x4 o;
    o[0] = t[0] | ((unsigned)t[1] << 16);
    o[1] = t[2] | ((unsigned)t[3] << 16);
    o[2] = t[4] | ((unsigned)t[5] << 16);
    o[3] = t[6] | ((unsigned)t[7] << 16);
    *(u32x4*)(ktg + (size_t)(c0 + oc) * E_N + r0 + seg2 * 8) = o;
  }
}

// Reg-staged tile load: 8 x global dwordx4 into named regs (L2-allocating,
// unlike global_load_lds whose fetches got 0% L2 hit across rounds 2-7).
#define LOADREGS(KV1)                                                           \
  {                                                                             \
    const u16* kp = kgp + (size_t)(KV1) * 128;                                  \
    kr0 = *(const u32x4*)(kp);                                                  \
    kr1 = *(const u32x4*)(kp + 16 * 128);                                       \
    kr2 = *(const u32x4*)(kp + 32 * 128);                                       \
    kr3 = *(const u32x4*)(kp + 48 * 128);                                       \
    const u16* tp = ktp + (KV1);                                                \
    tr0 = *(const u32x4*)(tp);                                                  \
    tr1 = *(const u32x4*)(tp + 32 * E_N);                                       \
    tr2 = *(const u32x4*)(tp + 64 * E_N);                                       \
    tr3 = *(const u32x4*)(tp + 96 * E_N);                                       \
  }

#define WRITELDS(KW, TW)                                                        \
  {                                                                             \
    *(u32x4*)((KW) + kofs)          = kr0;                                      \
    *(u32x4*)((KW) + kofs + 4096)   = kr1;                                      \
    *(u32x4*)((KW) + kofs + 8192)   = kr2;                                      \
    *(u32x4*)((KW) + kofs + 12288)  = kr3;                                      \
    *(u32x4*)((TW) + tofs)          = tr0;                                      \
    *(u32x4*)((TW) + tofs + 4096)   = tr1;                                      \
    *(u32x4*)((TW) + tofs + 8192)   = tr2;                                      \
    *(u32x4*)((TW) + tofs + 12288)  = tr3;                                      \
  }

// Fused mask path (replaces the separate k_pack pass): per step each wave
// loads its 16 q-rows x 64 kv-cols of int32 mask as 16 full-wave coalesced
// dword loads (256B bursts), ballots them into u64 row-masks (bit l = col l),
// and parks them in a wave-private LDS slot (no barrier needed).
#define MASKLOAD(KV1)                                                           \
  {                                                                             \
    _Pragma("unroll")                                                           \
    for (int j = 0; j < 16; ++j) mv[j] = mptr[(size_t)j * E_N + (KV1)];         \
  }

#define MASKBALLOT()                                                            \
  {                                                                             \
    u32 mlo = 0, mhi = 0;                                                       \
    _Pragma("unroll")                                                           \
    for (int j = 0; j < 16; ++j) {                                              \
      u64 b = __ballot(mv[j] != 0);                                             \
      if (lane == j) { mlo = (u32)b; mhi = (u32)(b >> 32); }                    \
    }                                                                           \
    if (lane < 16) { u32x2 o; o[0] = mlo; o[1] = mhi;                           \
      *(u32x2*)(MshW + lane * 2) = o; }                                         \
  }

// One flash step: issue next-tile reg loads + next-step mask loads, read this
// step's row-masks from wave-private LDS, compute QK^T -> masked exp2 -> PV,
// ballot+park next masks, barrier, ds_write next tile, barrier.
#define FSTEP(SUB, KR, TR, KW, TW, DOPF)                                        \
  {                                                                             \
    if (DOPF) {                                                                 \
      LOADREGS(kvbase + (st2 + (SUB) + 1) * 64)                                 \
      MASKLOAD(kvbase + (st2 + (SUB) + 1) * 64)                                 \
    }                                                                           \
    u32 wlo[4], whi[4];                                                         \
    _Pragma("unroll")                                                           \
    for (int r = 0; r < 4; ++r) {                                               \
      u32x2 t3 = *(const u32x2*)(MshW + (4 * g + r) * 2);                       \
      wlo[r] = t3[0]; whi[r] = t3[1];                                           \
    }                                                                           \
    f32x4 S[4];                                                                 \
    _Pragma("unroll")                                                           \
    for (int t = 0; t < 4; ++t) S[t] = zero4;                                   \
    _Pragma("unroll")                                                           \
    for (int t = 0; t < 4; ++t) {                                               \
      int krow = t * 16 + l15;                                                  \
      _Pragma("unroll")                                                         \
      for (int ks = 0; ks < 4; ++ks) {                                          \
        V16 kf; kf.q = *(const u32x4*)((KR) + (((krow << 8) + (ks << 6) + (g << 4)) ^ ((l15 & 7) << 4))); \
        S[t] = __builtin_amdgcn_mfma_f32_16x16x32_bf16(qf[ks], kf.h, S[t], 0, 0, 0); \
      }                                                                         \
    }                                                                           \
    _Pragma("unroll")                                                           \
    for (int t = 0; t < 4; ++t) {                                               \
      _Pragma("unroll")                                                         \
      for (int r = 0; r < 4; ++r) {                                             \
        u32 w = (t & 2) ? whi[r] : wlo[r];                                      \
        float pv = ((w >> ((t & 1) * 16 + l15)) & 1u)                           \
                       ? __builtin_amdgcn_exp2f(S[t][r]) : 0.f;                 \
        lacc[r] += pv;                                                          \
        int prow = 4 * g + r;                                                   \
        *(u16*)(Pw + ((prow * 128 + (t * 16 + l15) * 2) ^ ((prow & 7) << 4))) = f2bf(pv); \
      }                                                                         \
    }                                                                           \
    bf16x8 pa0, pa1;                                                            \
    { V16 t2; t2.q = *(const u32x4*)(Pw + ((l15 * 128 + g * 16) ^ ((l15 & 7) << 4))); pa0 = t2.h; } \
    { V16 t2; t2.q = *(const u32x4*)(Pw + ((l15 * 128 + 64 + g * 16) ^ ((l15 & 7) << 4))); pa1 = t2.h; } \
    _Pragma("unroll")                                                           \
    for (int dt = 0; dt < 8; ++dt) {                                            \
      int krow = dt * 16 + l15;                                                 \
      V16 kf0; kf0.q = *(const u32x4*)((TR) + (((krow << 7) + (g << 4)) ^ ((l15 & 7) << 4))); \
      Oacc[dt] = __builtin_amdgcn_mfma_f32_16x16x32_bf16(pa0, kf0.h, Oacc[dt], 0, 0, 0); \
      V16 kf1; kf1.q = *(const u32x4*)((TR) + (((krow << 7) + 64 + (g << 4)) ^ ((l15 & 7) << 4))); \
      Oacc[dt] = __builtin_amdgcn_mfma_f32_16x16x32_bf16(pa1, kf1.h, Oacc[dt], 0, 0, 0); \
    }                                                                           \
    if (DOPF) MASKBALLOT()                                                      \
    __syncthreads();                                                            \
    if (DOPF) WRITELDS(KW, TW)                                                  \
    __syncthreads();                                                            \
  }

// ---------- kernel 3: fused masked-softmax attention, reg-staged dbuf tiles,
// mask packed on the fly. grid 1024: split = bid&7 (XCD-aligned), qb = bid>>3.
__launch_bounds__(256, 2)
__global__ void k_flash(const u16* __restrict__ qg, const u16* __restrict__ kg,
                        const u16* __restrict__ ktg, const int* __restrict__ M,
                        float* __restrict__ Op, float* __restrict__ lp) {
  __shared__ __align__(16) char K0[64 * 256], K1[64 * 256];   // 2x16 KB
  __shared__ __align__(16) char T0[128 * 128], T1[128 * 128]; // 2x16 KB
  __shared__ __align__(16) char Psh[4 * 2048];                // per-wave P tile
  __shared__ __align__(8)  u32 Msh[4 * 32];                   // per-wave 16 u64 row-masks
  const int tid = threadIdx.x;
  const int wid = tid >> 6, lane = tid & 63, g = lane >> 4, l15 = lane & 15;
  const int bid = blockIdx.x;
  const int split = bid & 7, qb = bid >> 3;
  const int qb0 = qb * QBLK;
  const int kvbase = split * (E_N / SPLIT);
  char* Pw = Psh + wid * 2048;
  u32* MshW = Msh + wid * 32;
  const int* mptr = M + (size_t)(qb0 + wid * 16) * E_N + lane;
  int mv[16];

  // staging lane geometry (swizzled LDS dest, linear global source)
  const int kr_r = tid >> 4, kr_s = tid & 15;   // K: rows kr_r+16i, 16B seg kr_s
  const int tr_d = tid >> 3, tr_s = tid & 7;    // Kt: d tr_d+32i, 16B seg tr_s
  const int kofs = ((kr_r << 8) + (kr_s << 4)) ^ ((kr_r & 7) << 4);
  const int tofs = ((tr_d << 7) + (tr_s << 4)) ^ ((tr_d & 7) << 4);
  const u16* kgp = kg + (size_t)kr_r * 128 + kr_s * 8;
  const u16* ktp = ktg + (size_t)tr_d * E_N + tr_s * 8;
  u32x4 kr0, kr1, kr2, kr3, tr0, tr1, tr2, tr3;

  bf16x8 qf[4];
  {
    const u16* qrow = qg + (size_t)(qb0 + wid * 16 + l15) * 128;
#pragma unroll
    for (int ks = 0; ks < 4; ++ks) {
      V16 t; t.q = *(const u32x4*)(qrow + (ks << 5) + (g << 3));
      qf[ks] = t.h;
    }
  }
  const f32x4 zero4 = {0.f, 0.f, 0.f, 0.f};
  f32x4 Oacc[8];
#pragma unroll
  for (int i = 0; i < 8; ++i) Oacc[i] = zero4;
  float lacc[4] = {0.f, 0.f, 0.f, 0.f};

  // prologue: step-0 mask + tiles
  MASKLOAD(kvbase)
  MASKBALLOT()
  LOADREGS(kvbase)
  WRITELDS(K0, T0)
  __syncthreads();

  for (int st2 = 0; st2 < CH; st2 += 2) {
    FSTEP(0, K0, T0, K1, T1, true)
    FSTEP(1, K1, T1, K0, T0, (st2 < CH - 2))
  }

  // reduce row sums across the 16 lanes of each group
#pragma unroll
  for (int r = 0; r < 4; ++r) {
    float v = lacc[r];
    v += __shfl_xor(v, 1);
    v += __shfl_xor(v, 2);
    v += __shfl_xor(v, 4);
    v += __shfl_xor(v, 8);
    lacc[r] = v;
  }
  if (l15 == 0) {
#pragma unroll
    for (int r = 0; r < 4; ++r)
      lp[split * E_N + qb0 + wid * 16 + 4 * g + r] = lacc[r];
  }
  float* op = Op + ((size_t)split * E_N + qb0 + wid * 16) * 128;
#pragma unroll
  for (int dt = 0; dt < 8; ++dt)
#pragma unroll
    for (int r = 0; r < 4; ++r)
      op[(4 * g + r) * 128 + dt * 16 + l15] = Oacc[dt][r];
}

// ---------- kernel 4: combine KV-split partials, normalize (float4)
__global__ void k_comb(const float* __restrict__ Op, const float* __restrict__ lp,
                       float* __restrict__ out) {
  int idx4 = blockIdx.x * 256 + threadIdx.x;       // < 8192*128/4
  int base = idx4 << 2;
  int e = base >> 7;
  f32x4 o = {0.f, 0.f, 0.f, 0.f};
  float l = 0.f;
#pragma unroll
  for (int s = 0; s < SPLIT; ++s) {
    o += *(const f32x4*)(Op + (size_t)s * (E_N * 128) + base);
    l += lp[s * E_N + e];
  }
  float rl = 1.0f / l;
  o[0] *= rl; o[1] *= rl; o[2] *= rl; o[3] *= rl;
  *(f32x4*)(out + base) = o;
}

extern "C" void kernel_launch(void* const* d_in, const int* in_sizes, int n_in,
                              void* d_out, int out_size, void* d_ws, size_t ws_size,
                              hipStream_t stream) {
  const float* X  = (const float*)d_in[0];
  const float* Wq = (const float*)d_in[1];
  const float* Wk = (const float*)d_in[2];
  const int*   M  = (const int*)d_in[3];
  char* ws = (char*)d_ws;
  u16*   qg   = (u16*)(ws);                                       // 2 MB
  u16*   kg   = (u16*)(ws + (size_t)(2u << 20));                  // 2 MB
  u16*   ktg  = (u16*)(ws + (size_t)(4u << 20));                  // 2 MB
  u16*   wt   = (u16*)(ws + (size_t)(6u << 20));                  // 128 KB
  float* lp   = (float*)(ws + (size_t)(6u << 20) + (128u << 10)); // 256 KB
  float* Op   = (float*)(ws + (size_t)(6u << 20) + (512u << 10) + (8u << 20)); // 32 MB
  float* out = (float*)d_out;

  k_wt  <<<256, 256, 0, stream>>>(Wq, Wk, wt);
  k_proj<<<128, 256, 0, stream>>>(X, wt, qg, kg);
  k_kt  <<<256, 256, 0, stream>>>(kg, ktg);
  k_flash<<<SPLIT * (E_N / QBLK), 256, 0, stream>>>(qg, kg, ktg, M, Op, lp);
  k_comb<<<(E_N * 128 / 4) / 256, 256, 0, stream>>>(Op, lp, out);
}